// Round 6
// baseline (698.325 us; speedup 1.0000x reference)
//
#include <hip/hip_runtime.h>

#define NUM_NODES 262144
#define HIDDEN 256
#define NHID 128
#define NUM_GRAPHS 1024

typedef float f32x4 __attribute__((ext_vector_type(4)));
typedef short s16x8 __attribute__((ext_vector_type(8)));

// f32 -> bf16 bits with round-to-nearest-even
__device__ __forceinline__ short f2bf(float f) {
    unsigned u = __builtin_bit_cast(unsigned, f);
    unsigned r = (u + 0x7FFFu + ((u >> 16) & 1u)) >> 16;
    return (short)r;
}

// bf16 bits -> f32 (exact)
__device__ __forceinline__ float bf2f(short h) {
    return __builtin_bit_cast(float, ((unsigned)(unsigned short)h) << 16);
}

// tanh via native exp: ~6 VALU ops. Saturates correctly for large |v|.
__device__ __forceinline__ float fast_tanh(float v) {
    float e = __expf(2.0f * v);
    return 1.0f - __fdividef(2.0f, e + 1.0f);
}

// ---------------------------------------------------------------------------
// Kernel 0: swizzle W1 into bf16 MFMA fragment order + zero out/sums.
// ---------------------------------------------------------------------------
__global__ __launch_bounds__(256) void prep_w1(const float* __restrict__ W1,
                                               short* __restrict__ w1swz,
                                               float* __restrict__ out,
                                               float* __restrict__ sums) {
    int e = blockIdx.x * 256 + threadIdx.x;   // 0..4095
    f32x4 z = (f32x4){0.f, 0.f, 0.f, 0.f};
#pragma unroll
    for (int i = 0; i < 16; ++i)
        ((f32x4*)out)[e + i * 4096] = z;
    if (e < 256) ((f32x4*)sums)[e] = z;

    int l  = e & 63;
    int nt = (e >> 6) & 7;
    int kt = e >> 9;
    int kbase = kt * 32 + ((l >> 4) << 3);
    int n = nt * 16 + (l & 15);
#pragma unroll
    for (int j = 0; j < 8; ++j)
        w1swz[e * 8 + j] = f2bf(W1[(size_t)(kbase + j) * NHID + n]);
}

// ---------------------------------------------------------------------------
// Per-tile pooled contribution via XOR reduce-scatter over the 16 l15-lanes.
// Input: af[8] = this lane's node (l15) features in bf16, ew = its softmax
// weight (masked 0 at graph boundaries). Output: accp[4] — lane (quad,l15)
// accumulates 4 DISTINCT features summed over the tile's 16 nodes:
//   feature(a) = 128*(a>>1) + 64*(a&1) + 32*((l15>>3)&1) + 8*quad + (l15&7)
// Invariant after stage s: v[p] holds Sum over lanes with matching low-s
// bits of index i = (p<<s)|(l15 & ((1<<s)-1)).  accp shrinks 64->4 VGPRs,
// which is what gets fused_kernel under the 128-VGPR / 4-waves-per-SIMD line.
// ---------------------------------------------------------------------------
__device__ __forceinline__ void pool_rs(const s16x8* af, float* accp,
                                        float ew, int l15) {
#pragma unroll
    for (int h = 0; h < 2; ++h) {
        float v[32];
#pragma unroll
        for (int kt = 0; kt < 4; ++kt)
#pragma unroll
            for (int j = 0; j < 8; ++j)
                v[kt * 8 + j] = bf2f(af[h * 4 + kt][j]) * ew;
#pragma unroll
        for (int s = 0; s < 4; ++s) {
            int m = 1 << s;
            int b = (l15 >> s) & 1;
#pragma unroll
            for (int p = 0; p < 16; ++p) {
                if (p < (16 >> s)) {
                    float keep = b ? v[2 * p + 1] : v[2 * p];
                    float send = b ? v[2 * p] : v[2 * p + 1];
                    v[p] = keep + __shfl_xor(send, m);
                }
            }
        }
        accp[h * 2 + 0] += v[0];
        accp[h * 2 + 1] += v[1];
    }
}

// Flush: accp already holds per-feature sums -> 4 atomics/lane (256 features
// covered exactly once per wave); sum_e butterfly over l15 then one atomic.
#define FLUSH(G) do {                                                         \
    sum_e += __shfl_xor(sum_e, 1);                                            \
    sum_e += __shfl_xor(sum_e, 2);                                            \
    sum_e += __shfl_xor(sum_e, 4);                                            \
    sum_e += __shfl_xor(sum_e, 8);                                            \
    float* vrow_ = out + (size_t)(G) * HIDDEN + fbase;                        \
    atomicAdd(vrow_ + 0,   accp[0]);                                          \
    atomicAdd(vrow_ + 64,  accp[1]);                                          \
    atomicAdd(vrow_ + 128, accp[2]);                                          \
    atomicAdd(vrow_ + 192, accp[3]);                                          \
    if (l15 == 0 && quad == 0) atomicAdd(&sums[G], sum_e);                    \
    accp[0] = accp[1] = accp[2] = accp[3] = 0.f;                              \
    sum_e = 0.f;                                                              \
} while (0)

// ---------------------------------------------------------------------------
// Fused kernel: 512-thread blocks (8 waves), 512 blocks -> 2 blocks/CU
// (LDS 65.5 KB x2 fits 160 KB) x 8 waves = 16 waves/CU = 4 waves/SIMD,
// double R2-R5's occupancy. Wave owns 64 nodes (4 tiles of 16).
// ---------------------------------------------------------------------------
__global__ __launch_bounds__(512, 4) void fused_kernel(
    const float* __restrict__ x, const int* __restrict__ batch,
    const short* __restrict__ w1swz, const float* __restrict__ b1,
    const float* __restrict__ W2, const float* __restrict__ b2,
    float* __restrict__ out, float* __restrict__ sums) {
    __shared__ short w1s[32768];   // 64 KB fragment-ordered bf16 W1
    __shared__ float bw[256];      // [nt][quad][j]: j<4 -> b1, j>=4 -> W2

    int tid = threadIdx.x;
    for (int i = tid; i < 4096; i += 512)
        ((f32x4*)w1s)[i] = ((const f32x4*)w1swz)[i];
    if (tid < 256) {
        int nt = tid >> 5, q = (tid >> 3) & 3, j = tid & 7;
        bw[tid] = (j < 4) ? b1[nt * 16 + q * 4 + j]
                          : W2[nt * 16 + q * 4 + (j - 4)];
    }
    __syncthreads();

    int wave = tid >> 6, lane = tid & 63;
    int quad = lane >> 4, l15 = lane & 15;
    float b2v = b2[0];
    int fbase = ((l15 >> 3) & 1) * 32 + quad * 8 + (l15 & 7);

    float accp[4] = {0.f, 0.f, 0.f, 0.f};
    float sum_e = 0.f;
    int base = blockIdx.x * 512 + wave * 64;   // wave owns 64 contiguous nodes
    int cur_g = batch[base];

    for (int g = 0; g < 4; ++g) {
        int row = base + g * 16 + l15;
        int my_g = batch[row];
        const float* xrow = x + (size_t)row * HIDDEN + quad * 8;

        // load + convert in two half-tiles (a[8] transient, low reg pressure)
        s16x8 af[8];
#pragma unroll
        for (int h = 0; h < 2; ++h) {
            f32x4 a[8];
#pragma unroll
            for (int kt = 0; kt < 4; ++kt) {
                a[2 * kt]     = *(const f32x4*)(xrow + (h * 4 + kt) * 32);
                a[2 * kt + 1] = *(const f32x4*)(xrow + (h * 4 + kt) * 32 + 4);
            }
#pragma unroll
            for (int kt = 0; kt < 4; ++kt) {
                f32x4 a0 = a[2 * kt], a1 = a[2 * kt + 1];
                s16x8 f;
                f[0] = f2bf(a0.x); f[1] = f2bf(a0.y);
                f[2] = f2bf(a0.z); f[3] = f2bf(a0.w);
                f[4] = f2bf(a1.x); f[5] = f2bf(a1.y);
                f[6] = f2bf(a1.z); f[7] = f2bf(a1.w);
                af[h * 4 + kt] = f;
            }
        }

        // Ht = W1^T @ X^T (swapped-operand MFMA)
        f32x4 acc[8];
#pragma unroll
        for (int nt = 0; nt < 8; ++nt) acc[nt] = (f32x4){0.f, 0.f, 0.f, 0.f};
#pragma unroll
        for (int kt = 0; kt < 8; ++kt) {
#pragma unroll
            for (int nt = 0; nt < 8; ++nt) {
                s16x8 bf = *(const s16x8*)&w1s[((kt * 8 + nt) * 64 + lane) * 8];
                acc[nt] = __builtin_amdgcn_mfma_f32_16x16x32_bf16(bf, af[kt], acc[nt], 0, 0, 0);
            }
        }

        // score -> every lane holds s for its own node l15
        float p = 0.f;
#pragma unroll
        for (int nt = 0; nt < 8; ++nt) {
            f32x4 b1q = *(f32x4*)&bw[nt * 32 + quad * 8];
            f32x4 w2q = *(f32x4*)&bw[nt * 32 + quad * 8 + 4];
#pragma unroll
            for (int r = 0; r < 4; ++r)
                p += fast_tanh(acc[nt][r] + b1q[r]) * w2q[r];
        }
        p += __shfl_xor(p, 16);
        p += __shfl_xor(p, 32);
        float e = __expf(p + b2v);

        // segmented pooling (tile spans <=2 graphs: sizes are 256±16)
        int first_g = __shfl(my_g, 0);
        int last_g  = __shfl(my_g, 15);
        if (first_g != cur_g) { FLUSH(cur_g); cur_g = first_g; }
        if (last_g == cur_g) {
            pool_rs(af, accp, e, l15);
            sum_e += e;
        } else {
            float e0 = (my_g == cur_g) ? e : 0.f;
            pool_rs(af, accp, e0, l15);
            sum_e += e0;
            FLUSH(cur_g);
            float e1 = (my_g == last_g) ? e : 0.f;
            pool_rs(af, accp, e1, l15);
            sum_e += e1;
            cur_g = last_g;
        }
    }
    FLUSH(cur_g);
}

// ---------------------------------------------------------------------------
// Finalize in place: out[g][c] /= (sums[g] + 1e-8)
// ---------------------------------------------------------------------------
__global__ __launch_bounds__(256) void norm_kernel(
    float* __restrict__ out, const float* __restrict__ sums) {
    int idx = blockIdx.x * 256 + threadIdx.x;
    float inv = 1.0f / (sums[idx >> 8] + 1e-8f);
    out[idx] = out[idx] * inv;
}

extern "C" void kernel_launch(void* const* d_in, const int* in_sizes, int n_in,
                              void* d_out, int out_size, void* d_ws, size_t ws_size,
                              hipStream_t stream) {
    const float* x     = (const float*)d_in[0];
    const int*   batch = (const int*)d_in[1];
    const float* W1    = (const float*)d_in[2];
    const float* b1    = (const float*)d_in[3];
    const float* W2    = (const float*)d_in[4];
    const float* b2    = (const float*)d_in[5];
    float* out = (float*)d_out;

    char* ws = (char*)d_ws;
    float* sums  = (float*)ws;                          // 4 KB
    short* w1swz = (short*)(ws + NUM_GRAPHS * 4);       // 64 KB

    hipLaunchKernelGGL(prep_w1, dim3(16), dim3(256), 0, stream,
                       W1, w1swz, out, sums);
    hipLaunchKernelGGL(fused_kernel, dim3(512), dim3(512), 0, stream,
                       x, batch, w1swz, b1, W2, b2, out, sums);
    hipLaunchKernelGGL(norm_kernel, dim3(NUM_GRAPHS * HIDDEN / 256), dim3(256), 0, stream,
                       out, sums);
}

// Round 7
// 386.554 us; speedup vs baseline: 1.8065x; 1.8065x over previous
//
#include <hip/hip_runtime.h>

#define NUM_NODES 262144
#define HIDDEN 256
#define NHID 128
#define NUM_GRAPHS 1024

typedef float f32x4 __attribute__((ext_vector_type(4)));
typedef short s16x8 __attribute__((ext_vector_type(8)));
typedef unsigned int u32x2 __attribute__((ext_vector_type(2)));

// f32 -> bf16 bits with round-to-nearest-even
__device__ __forceinline__ short f2bf(float f) {
    unsigned u = __builtin_bit_cast(unsigned, f);
    unsigned r = (u + 0x7FFFu + ((u >> 16) & 1u)) >> 16;
    return (short)r;
}
__device__ __forceinline__ unsigned pack2(float lo, float hi) {
    return ((unsigned)(unsigned short)f2bf(hi) << 16) | (unsigned)(unsigned short)f2bf(lo);
}

// bf16 bits -> f32 (exact)
__device__ __forceinline__ float bf2f(short h) {
    return __builtin_bit_cast(float, ((unsigned)(unsigned short)h) << 16);
}

// tanh via native exp: ~6 VALU ops. Saturates correctly for large |v|.
__device__ __forceinline__ float fast_tanh(float v) {
    float e = __expf(2.0f * v);
    return 1.0f - __fdividef(2.0f, e + 1.0f);
}

// ---------------------------------------------------------------------------
// Kernel 0: swizzle W1 into bf16 MFMA fragment order + zero out/sums.
// ---------------------------------------------------------------------------
__global__ __launch_bounds__(256) void prep_w1(const float* __restrict__ W1,
                                               short* __restrict__ w1swz,
                                               float* __restrict__ out,
                                               float* __restrict__ sums) {
    int e = blockIdx.x * 256 + threadIdx.x;   // 0..4095
    f32x4 z = (f32x4){0.f, 0.f, 0.f, 0.f};
#pragma unroll
    for (int i = 0; i < 16; ++i)
        ((f32x4*)out)[e + i * 4096] = z;
    if (e < 256) ((f32x4*)sums)[e] = z;

    int l  = e & 63;
    int nt = (e >> 6) & 7;
    int kt = e >> 9;
    int kbase = kt * 32 + ((l >> 4) << 3);
    int n = nt * 16 + (l & 15);
#pragma unroll
    for (int j = 0; j < 8; ++j)
        w1swz[e * 8 + j] = f2bf(W1[(size_t)(kbase + j) * NHID + n]);
}

// ---------------------------------------------------------------------------
// Fused kernel with COALESCED x loads.
// R0-R5's fragment-direct loads were 16 x 64B scattered segments per
// instruction (~2.1 TB/s, 33% HBM duty). Now: instruction t reads row t of
// the tile as ONE 1KB contiguous segment (lane l takes bytes 16l..16l+16),
// packs to bf16, stages through a WAVE-PRIVATE XOR-swizzled 8KB LDS tile
// (no barriers), and reads MFMA fragments back conflict-free.
// Everything downstream (MFMA/score/pool/flush) is R5's proven-clean code.
// ---------------------------------------------------------------------------
#define FLUSH(G) do {                                                         \
    _Pragma("unroll")                                                         \
    for (int m_ = 1; m_ <= 8; m_ <<= 1) {                                     \
        _Pragma("unroll")                                                     \
        for (int i_ = 0; i_ < 16; ++i_) {                                     \
            accp[i_].x += __shfl_xor(accp[i_].x, m_);                         \
            accp[i_].y += __shfl_xor(accp[i_].y, m_);                         \
            accp[i_].z += __shfl_xor(accp[i_].z, m_);                         \
            accp[i_].w += __shfl_xor(accp[i_].w, m_);                         \
        }                                                                     \
        sum_e += __shfl_xor(sum_e, m_);                                       \
    }                                                                         \
    if (l15 == 0) {                                                           \
        float* vrow_ = out + (size_t)(G) * HIDDEN;                            \
        _Pragma("unroll")                                                     \
        for (int i_ = 0; i_ < 16; ++i_) {                                     \
            int colb_ = (i_ >> 1) * 32 + quad * 8 + (i_ & 1) * 4;             \
            atomicAdd(vrow_ + colb_ + 0, accp[i_].x);                         \
            atomicAdd(vrow_ + colb_ + 1, accp[i_].y);                         \
            atomicAdd(vrow_ + colb_ + 2, accp[i_].z);                         \
            atomicAdd(vrow_ + colb_ + 3, accp[i_].w);                         \
        }                                                                     \
        if (quad == 0) atomicAdd(&sums[G], sum_e);                            \
    }                                                                         \
    _Pragma("unroll")                                                         \
    for (int i_ = 0; i_ < 16; ++i_) accp[i_] = (f32x4){0.f, 0.f, 0.f, 0.f};   \
    sum_e = 0.f;                                                              \
} while (0)

// accp += (bf16 x, exact unpack) * EW ; sum_e += EW
#define POOL(EW) do {                                                         \
    _Pragma("unroll")                                                         \
    for (int kt_ = 0; kt_ < 8; ++kt_) {                                       \
        accp[2 * kt_].x     += bf2f(af[kt_][0]) * (EW);                       \
        accp[2 * kt_].y     += bf2f(af[kt_][1]) * (EW);                       \
        accp[2 * kt_].z     += bf2f(af[kt_][2]) * (EW);                       \
        accp[2 * kt_].w     += bf2f(af[kt_][3]) * (EW);                       \
        accp[2 * kt_ + 1].x += bf2f(af[kt_][4]) * (EW);                       \
        accp[2 * kt_ + 1].y += bf2f(af[kt_][5]) * (EW);                       \
        accp[2 * kt_ + 1].z += bf2f(af[kt_][6]) * (EW);                       \
        accp[2 * kt_ + 1].w += bf2f(af[kt_][7]) * (EW);                       \
    }                                                                         \
    sum_e += (EW);                                                            \
} while (0)

__global__ __launch_bounds__(512, 2) void fused_kernel(
    const float* __restrict__ x, const int* __restrict__ batch,
    const short* __restrict__ w1swz, const float* __restrict__ b1,
    const float* __restrict__ W2, const float* __restrict__ b2,
    float* __restrict__ out, float* __restrict__ sums) {
    __shared__ short w1s[32768];   // 64 KB fragment-ordered bf16 W1
    __shared__ short xs[32768];    // 64 KB: 8 waves x 8 KB private x tiles
    __shared__ float bw[256];      // [nt][quad][j]: j<4 -> b1, j>=4 -> W2

    int tid = threadIdx.x;
    for (int i = tid; i < 4096; i += 512)
        ((f32x4*)w1s)[i] = ((const f32x4*)w1swz)[i];
    if (tid < 256) {
        int nt = tid >> 5, q = (tid >> 3) & 3, j = tid & 7;
        bw[tid] = (j < 4) ? b1[nt * 16 + q * 4 + j]
                          : W2[nt * 16 + q * 4 + (j - 4)];
    }
    __syncthreads();   // only barrier: xs is wave-private afterwards

    int wave = tid >> 6, lane = tid & 63;
    int quad = lane >> 4, l15 = lane & 15;
    float b2v = b2[0];
    char* xsb = (char*)xs + wave * 8192;   // this wave's 16-row bf16 tile

    f32x4 accp[16];
#pragma unroll
    for (int i = 0; i < 16; ++i) accp[i] = (f32x4){0.f, 0.f, 0.f, 0.f};
    float sum_e = 0.f;
    int base = blockIdx.x * 1024 + wave * 128;  // wave owns 128 contiguous nodes
    int cur_g = batch[base];

    for (int g = 0; g < 8; ++g) {
        int row0 = base + g * 16;
        int my_g = batch[row0 + l15];

        // 1) coalesced loads: instr t = full row t, 1KB contiguous segment
        f32x4 a[16];
#pragma unroll
        for (int t = 0; t < 16; ++t)
            a[t] = ((const f32x4*)(x + (size_t)(row0 + t) * HIDDEN))[lane];

        // 2) pack f32->bf16, swizzled ds_write (row t uniform per instr;
        //    XOR (t&7)<<4 permutes within the 512B row -> still 4cy writes)
#pragma unroll
        for (int t = 0; t < 16; ++t) {
            u32x2 d;
            d.x = pack2(a[t].x, a[t].y);
            d.y = pack2(a[t].z, a[t].w);
            *(u32x2*)(xsb + t * 512 + ((lane * 8) ^ ((t & 7) << 4))) = d;
        }

        // 3) fragment read-back, conflict-free under matching XOR:
        //    af[kt] = x[row l15][kt*32 + quad*8 .. +8) in bf16
        s16x8 af[8];
#pragma unroll
        for (int kt = 0; kt < 8; ++kt)
            af[kt] = *(const s16x8*)(xsb + l15 * 512 +
                                     ((quad * 16 + kt * 64) ^ ((l15 & 7) << 4)));

        // 4) Ht = W1^T @ X^T (swapped-operand MFMA)
        f32x4 acc[8];
#pragma unroll
        for (int nt = 0; nt < 8; ++nt) acc[nt] = (f32x4){0.f, 0.f, 0.f, 0.f};
#pragma unroll
        for (int kt = 0; kt < 8; ++kt) {
#pragma unroll
            for (int nt = 0; nt < 8; ++nt) {
                s16x8 bf = *(const s16x8*)&w1s[((kt * 8 + nt) * 64 + lane) * 8];
                acc[nt] = __builtin_amdgcn_mfma_f32_16x16x32_bf16(bf, af[kt], acc[nt], 0, 0, 0);
            }
        }

        // 5) score -> every lane holds s for its own node l15
        float p = 0.f;
#pragma unroll
        for (int nt = 0; nt < 8; ++nt) {
            f32x4 b1q = *(f32x4*)&bw[nt * 32 + quad * 8];
            f32x4 w2q = *(f32x4*)&bw[nt * 32 + quad * 8 + 4];
#pragma unroll
            for (int r = 0; r < 4; ++r)
                p += fast_tanh(acc[nt][r] + b1q[r]) * w2q[r];
        }
        p += __shfl_xor(p, 16);
        p += __shfl_xor(p, 32);
        float e = __expf(p + b2v);

        // 6) segmented pooling, straight-line (tile spans <=2 graphs:
        //    graph sizes are 256±16 >> 16)
        int first_g = __shfl(my_g, 0);
        int last_g  = __shfl(my_g, 15);
        if (first_g != cur_g) { FLUSH(cur_g); cur_g = first_g; }
        if (last_g == cur_g) {
            POOL(e);
        } else {
            float e0 = (my_g == cur_g) ? e : 0.f;
            POOL(e0);
            FLUSH(cur_g);
            float e1 = (my_g == last_g) ? e : 0.f;
            POOL(e1);
            cur_g = last_g;
        }
    }
    FLUSH(cur_g);
}

// ---------------------------------------------------------------------------
// Finalize in place: out[g][c] /= (sums[g] + 1e-8)
// ---------------------------------------------------------------------------
__global__ __launch_bounds__(256) void norm_kernel(
    float* __restrict__ out, const float* __restrict__ sums) {
    int idx = blockIdx.x * 256 + threadIdx.x;
    float inv = 1.0f / (sums[idx >> 8] + 1e-8f);
    out[idx] = out[idx] * inv;
}

extern "C" void kernel_launch(void* const* d_in, const int* in_sizes, int n_in,
                              void* d_out, int out_size, void* d_ws, size_t ws_size,
                              hipStream_t stream) {
    const float* x     = (const float*)d_in[0];
    const int*   batch = (const int*)d_in[1];
    const float* W1    = (const float*)d_in[2];
    const float* b1    = (const float*)d_in[3];
    const float* W2    = (const float*)d_in[4];
    const float* b2    = (const float*)d_in[5];
    float* out = (float*)d_out;

    char* ws = (char*)d_ws;
    float* sums  = (float*)ws;                          // 4 KB
    short* w1swz = (short*)(ws + NUM_GRAPHS * 4);       // 64 KB

    hipLaunchKernelGGL(prep_w1, dim3(16), dim3(256), 0, stream,
                       W1, w1swz, out, sums);
    hipLaunchKernelGGL(fused_kernel, dim3(256), dim3(512), 0, stream,
                       x, batch, w1swz, b1, W2, b2, out, sums);
    hipLaunchKernelGGL(norm_kernel, dim3(NUM_GRAPHS * HIDDEN / 256), dim3(256), 0, stream,
                       out, sums);
}